// Round 1
// 538.288 us; speedup vs baseline: 1.0276x; 1.0276x over previous
//
#include <hip/hip_runtime.h>
#include <math.h>

// Problem constants: B=16, N=1024, F=64, T=24, K=3, FO=64
#define Bc 16
#define Nc 1024
#define Fc 64
#define Tc 24
#define Kc 3
#define FOc 64
#define Cc (Fc*Tc)      // 1536
#define KKc (Kc*Nc)     // 3072 = fused reduction length

typedef __attribute__((ext_vector_type(8))) short short8;   // 8 bf16 (4 VGPRs)
typedef __attribute__((ext_vector_type(8))) unsigned short u16x8;
typedef __attribute__((ext_vector_type(4))) float f32x4;

__device__ __forceinline__ unsigned short f2bf(float f) {
  unsigned u = __float_as_uint(f);
  u += 0x7fff + ((u >> 16) & 1);   // round-to-nearest-even
  return (unsigned short)(u >> 16);
}
__device__ __forceinline__ float bf2f(unsigned short h) {
  return __uint_as_float((unsigned)h << 16);
}

#define GLL16(g, l) __builtin_amdgcn_global_load_lds( \
    (const __attribute__((address_space(1))) void*)(g), \
    (__attribute__((address_space(3))) void*)(l), 16, 0, 0)

__device__ __forceinline__ f32x4 mfma16(short8 a, short8 b, f32x4 c) {
  return __builtin_amdgcn_mfma_f32_16x16x32_bf16(a, b, c, 0, 0, 0);
}

// ---------------------------------------------------------------------------
// GEMM core: 128x128 tile, BK=64, XOR-swizzled LDS (conflict-free, R4-verified).
// ---------------------------------------------------------------------------
__device__ __forceinline__ void gemm_core(
    const unsigned short* __restrict__ Ag, const unsigned short* __restrict__ Bg,
    int lda, int ldb, int K,
    unsigned short* As, unsigned short* Bs,
    int wave, int lane, f32x4 acc[4][4]) {
  int sr = lane >> 3;                    // row within a 1KB staging call
  int sc = ((lane & 7) ^ sr) * 8;        // swizzled source column (elems)
  const unsigned short* a0 = Ag + (size_t)(wave * 32 + sr) * lda + sc;
  const unsigned short* b0 = Bg + (size_t)(wave * 32 + sr) * ldb + sc;
  unsigned short* asw = As + (wave * 32) * 64;
  unsigned short* bsw = Bs + (wave * 32) * 64;
  int rw = (wave >> 1) * 64, cw = (wave & 1) * 64;
  int frow = lane & 15;
  int q = lane >> 4;
  int p0 = (q ^ (frow & 7)) * 8;         // half 0 chunk offset (elems)
  int p1 = ((q | 4) ^ (frow & 7)) * 8;   // half 1
  for (int k0 = 0; k0 < K; k0 += 64) {
    #pragma unroll
    for (int c = 0; c < 4; ++c) {
      GLL16(a0 + (size_t)(c * 8) * lda + k0, asw + (c * 8) * 64);
      GLL16(b0 + (size_t)(c * 8) * ldb + k0, bsw + (c * 8) * 64);
    }
    __syncthreads();
    #pragma unroll
    for (int h = 0; h < 2; ++h) {
      int p = h ? p1 : p0;
      short8 afr[4], bfr[4];
      #pragma unroll
      for (int i = 0; i < 4; ++i)
        afr[i] = *(const short8*)&As[(rw + i * 16 + frow) * 64 + p];
      #pragma unroll
      for (int j = 0; j < 4; ++j)
        bfr[j] = *(const short8*)&Bs[(cw + j * 16 + frow) * 64 + p];
      #pragma unroll
      for (int i = 0; i < 4; ++i)
        #pragma unroll
        for (int j = 0; j < 4; ++j)
          acc[i][j] = mfma16(afr[i], bfr[j], acc[i][j]);
    }
    __syncthreads();
  }
}

// ---------------------------------------------------------------------------
// xprep: single pass over x producing xt2[b][n][t][f] (bf16) AND
// lhsb/rhsb (bf16, K-padded to 64 with zeros) for the MFMA attention GEMM.
// ---------------------------------------------------------------------------
__global__ __launch_bounds__(256) void xprep_kernel(
    const float* __restrict__ x, const float* __restrict__ W1,
    const float* __restrict__ W2, const float* __restrict__ W3,
    unsigned short* __restrict__ xt2, unsigned short* __restrict__ lhsb,
    unsigned short* __restrict__ rhsb) {
  __shared__ float ld[4 * 1560];   // per wave: [t][f] stride 65 (pad)
  __shared__ float af[4 * 64];
  int w = threadIdx.x >> 6, lane = threadIdx.x & 63;
  size_t n = (size_t)blockIdx.x * 4 + w;
  const float* xp = x + n * Cc;
  float* lw = ld + w * 1560;
  #pragma unroll
  for (int j = 0; j < 24; ++j) {
    int i = j * 64 + lane;
    int f = i / 24, t = i - f * 24;
    lw[t * 65 + f] = xp[i];
  }
  __syncthreads();
  float a = 0.f;
  #pragma unroll
  for (int t = 0; t < Tc; ++t) a += lw[t * 65 + lane] * W1[t];
  af[w * 64 + lane] = a;
  #pragma unroll
  for (int j = 0; j < 24; ++j)
    xt2[n * Cc + j * 64 + lane] = f2bf(lw[j * 65 + lane]);
  __syncthreads();
  float l = 0.f, r = 0.f;
  if (lane < Tc) {
    #pragma unroll 8
    for (int f = 0; f < Fc; ++f) {
      l += af[w * 64 + f] * W2[f * Tc + lane];
      r += W3[f] * lw[lane * 65 + f];
    }
  }
  lhsb[n * 64 + lane] = (lane < Tc) ? f2bf(l) : (unsigned short)0;
  rhsb[n * 64 + lane] = (lane < Tc) ? f2bf(r) : (unsigned short)0;
}

// ---------------------------------------------------------------------------
// misc: Vs->bf16 (blocks 0..1023), tcat (1024..1087), bsT transpose (1088..1343)
// ---------------------------------------------------------------------------
__global__ __launch_bounds__(256) void misc_kernel(
    const float* __restrict__ Vs, const float* __restrict__ Theta,
    const float* __restrict__ bs, unsigned short* __restrict__ Vsbf,
    unsigned short* __restrict__ tcat, float* __restrict__ bsT) {
  __shared__ float t[64 * 65];
  int bid = blockIdx.x, tid = threadIdx.x;
  if (bid < 1024) {
    int i = (bid * 256 + tid) * 4;
    float4 v = *(const float4*)&Vs[i];
    ushort4 o;
    o.x = f2bf(v.x); o.y = f2bf(v.y); o.z = f2bf(v.z); o.w = f2bf(v.w);
    *(ushort4*)&Vsbf[i] = o;
  } else if (bid < 1088) {
    int i = (bid - 1024) * 256 + tid;   // 0..16383
    int m2 = i >> 6, f = i & 63;
    int k = m2 >> 6, o = m2 & 63;
    tcat[i] = (m2 < 192) ? f2bf(Theta[((size_t)k * Fc + f) * FOc + o])
                         : (unsigned short)0;
  } else {
    int id = bid - 1088;                 // 0..255: bsT[p][q] = bs[q][p]
    int p0 = (id >> 4) * 64, q0 = (id & 15) * 64;
    #pragma unroll
    for (int s = 0; s < 4; ++s) {
      int qr = (tid >> 4) + s * 16, pc = (tid & 15) * 4;
      float4 v = *(const float4*)&bs[(size_t)(q0 + qr) * Nc + p0 + pc];
      t[(pc + 0) * 65 + qr] = v.x;
      t[(pc + 1) * 65 + qr] = v.y;
      t[(pc + 2) * 65 + qr] = v.z;
      t[(pc + 3) * 65 + qr] = v.w;
    }
    __syncthreads();
    #pragma unroll
    for (int s = 0; s < 4; ++s) {
      int pr = (tid >> 4) + s * 16, qc = (tid & 15) * 4;
      float4 v = {t[pr * 65 + qc], t[pr * 65 + qc + 1],
                  t[pr * 65 + qc + 2], t[pr * 65 + qc + 3]};
      *(float4*)&bsT[(size_t)(p0 + pr) * Nc + q0 + qc] = v;
    }
  }
}

// ---------------------------------------------------------------------------
// chebT[k][m][n] = cheb[k][n][m] (fp32 transpose)
// ---------------------------------------------------------------------------
__global__ __launch_bounds__(256) void chebT_kernel(
    const float* __restrict__ cheb, float* __restrict__ chebT) {
  int k = blockIdx.z;
  int n0 = blockIdx.y * 64, m0 = blockIdx.x * 64;
  __shared__ float t[64 * 65];
  const float* src = cheb + (size_t)k * Nc * Nc;
  float* dst = chebT + (size_t)k * Nc * Nc;
  int tid = threadIdx.x;
  #pragma unroll
  for (int s = 0; s < 4; ++s) {
    int nr = (tid >> 4) + s * 16, mc = (tid & 15) * 4;
    float4 v = *(const float4*)&src[(size_t)(n0 + nr) * Nc + m0 + mc];
    t[(mc + 0) * 65 + nr] = v.x;
    t[(mc + 1) * 65 + nr] = v.y;
    t[(mc + 2) * 65 + nr] = v.z;
    t[(mc + 3) * 65 + nr] = v.w;
  }
  __syncthreads();
  #pragma unroll
  for (int s = 0; s < 4; ++s) {
    int mr = (tid >> 4) + s * 16, nc = (tid & 15) * 4;
    float4 v = {t[mr * 65 + nc], t[mr * 65 + nc + 1], t[mr * 65 + nc + 2], t[mr * 65 + nc + 3]};
    *(float4*)&dst[(size_t)(m0 + mr) * Nc + n0 + nc] = v;
  }
}

// ---------------------------------------------------------------------------
// masksoft: per (bl,m) row of ST: softmax over n (fp32), then
// Acat[bl][m][k*1024+n] = bf16(chebT[k][m][n] * softmax_n)
// ---------------------------------------------------------------------------
__global__ __launch_bounds__(256) void masksoft_kernel(
    const float* __restrict__ chebT, const unsigned short* __restrict__ ST,
    unsigned short* __restrict__ Acat, int bbase) {
  int m  = blockIdx.x & (Nc - 1);
  int bl = blockIdx.x >> 10;
  int tid = threadIdx.x;
  const unsigned short* sp = ST + ((size_t)(bbase + bl) * Nc + m) * Nc;
  ushort4 s4 = *(const ushort4*)(sp + tid * 4);
  float v0 = bf2f(s4.x), v1 = bf2f(s4.y), v2 = bf2f(s4.z), v3 = bf2f(s4.w);
  __shared__ float redm[4], reds[4];
  int wave = tid >> 6, lane = tid & 63;
  float mx = fmaxf(fmaxf(v0, v1), fmaxf(v2, v3));
  #pragma unroll
  for (int off = 32; off; off >>= 1) mx = fmaxf(mx, __shfl_xor(mx, off));
  if (lane == 0) redm[wave] = mx;
  __syncthreads();
  mx = fmaxf(fmaxf(redm[0], redm[1]), fmaxf(redm[2], redm[3]));
  float e0 = __expf(v0 - mx), e1 = __expf(v1 - mx);
  float e2 = __expf(v2 - mx), e3 = __expf(v3 - mx);
  float sm = e0 + e1 + e2 + e3;
  #pragma unroll
  for (int off = 32; off; off >>= 1) sm += __shfl_xor(sm, off);
  if (lane == 0) reds[wave] = sm;
  __syncthreads();
  float inv = 1.f / (reds[0] + reds[1] + reds[2] + reds[3]);
  e0 *= inv; e1 *= inv; e2 *= inv; e3 *= inv;
  unsigned short* ap = Acat + ((size_t)bl * Nc + m) * KKc + tid * 4;
  #pragma unroll
  for (int k = 0; k < Kc; ++k) {
    float4 c = *(const float4*)&chebT[((size_t)k * Nc + m) * Nc + tid * 4];
    ushort4 o;
    o.x = f2bf(c.x * e0); o.y = f2bf(c.y * e1);
    o.z = f2bf(c.z * e2); o.w = f2bf(c.w * e3);
    *(ushort4*)(ap + k * Nc) = o;
  }
}

// ---------------------------------------------------------------------------
// MFMA GEMM: C[m][n] = sum_k A[m][k]*B[n][k].
// MODE 0: bf16 C. MODE 1: fp32 relu C. MODE 2: bf16 sigmoid(C + bias[m][n]).
// XCD-aware bijective swizzle (m204): each XCD owns a contiguous batch-major
// chunk of blocks so operand-panel re-reads hit that XCD's private L2.
// Final GEMM: nwg=768 -> exactly one batch per XCD.
// ---------------------------------------------------------------------------
template <int MODE>
__global__ __launch_bounds__(256) void mfma_gemm_bt(
    const unsigned short* __restrict__ A, const unsigned short* __restrict__ B,
    void* __restrict__ Cv, const float* __restrict__ bias, int K, int CN,
    long long Abatch, long long Bbatch, long long Cbatch) {
  __shared__ unsigned short As[128 * 64];
  __shared__ unsigned short Bs[128 * 64];
  int gx = gridDim.x, gy = gridDim.y;
  int nwg = gx * gy * gridDim.z;
  int bid = blockIdx.x + gx * (blockIdx.y + gy * blockIdx.z);
  int xcd = bid & 7, idx = bid >> 3;
  int qq = nwg >> 3, rr = nwg & 7;
  int lin = (xcd < rr ? xcd * (qq + 1) : rr * (qq + 1) + (xcd - rr) * qq) + idx;
  int b = lin / (gx * gy);
  int rem = lin - b * (gx * gy);
  int by = rem / gx, bx = rem - by * gx;
  int tid = threadIdx.x, wave = tid >> 6, lane = tid & 63;
  const unsigned short* Ag = A + (size_t)b * Abatch + (size_t)by * 128 * K;
  const unsigned short* Bg = B + (size_t)b * Bbatch + (size_t)bx * 128 * K;
  f32x4 zero = {0.f, 0.f, 0.f, 0.f};
  f32x4 acc[4][4];
  #pragma unroll
  for (int i = 0; i < 4; ++i)
    #pragma unroll
    for (int j = 0; j < 4; ++j) acc[i][j] = zero;
  gemm_core(Ag, Bg, K, K, K, As, Bs, wave, lane, acc);
  int rw = (wave >> 1) * 64, cw = (wave & 1) * 64;
  int q = lane >> 4, cl = lane & 15;
  #pragma unroll
  for (int i = 0; i < 4; ++i)
    #pragma unroll
    for (int e = 0; e < 4; ++e) {
      size_t P = (size_t)by * 128 + rw + i * 16 + q * 4 + e;
      #pragma unroll
      for (int j = 0; j < 4; ++j) {
        size_t Q = (size_t)bx * 128 + cw + j * 16 + cl;
        if (MODE == 0) {
          ((unsigned short*)Cv)[(size_t)b * Cbatch + P * CN + Q] = f2bf(acc[i][j][e]);
        } else if (MODE == 1) {
          ((float*)Cv)[(size_t)b * Cbatch + P * CN + Q] = fmaxf(acc[i][j][e], 0.f);
        } else {
          float v = acc[i][j][e] + bias[P * CN + Q];
          ((unsigned short*)Cv)[(size_t)b * Cbatch + P * CN + Q] =
              f2bf(1.f / (1.f + __expf(-v)));
        }
      }
    }
}

// ---------------------------------------------------------------------------
// y2 GEMM: for z=(bl,t): ycat[bl][(o*24+t)][k*1024+n] =
//   sum_f tcat[(k*64+o)][f] * xt2[bbase+bl][n][t][f].  K=64.
// ---------------------------------------------------------------------------
__global__ __launch_bounds__(256) void y2_gemm(
    const unsigned short* __restrict__ tcat, const unsigned short* __restrict__ xt2,
    unsigned short* __restrict__ ycat, int bbase) {
  __shared__ unsigned short As[128 * 64];
  __shared__ unsigned short Bs[128 * 64];
  int z = blockIdx.z;
  int bl = z / 24, t = z - bl * 24;
  int tid = threadIdx.x, wave = tid >> 6, lane = tid & 63;
  const unsigned short* Ag = tcat + (size_t)blockIdx.y * 128 * 64;
  const unsigned short* Bg = xt2 + ((size_t)(bbase + bl) * Nc + (size_t)blockIdx.x * 128) * Cc
                             + (size_t)t * 64;
  f32x4 zero = {0.f, 0.f, 0.f, 0.f};
  f32x4 acc[4][4];
  #pragma unroll
  for (int i = 0; i < 4; ++i)
    #pragma unroll
    for (int j = 0; j < 4; ++j) acc[i][j] = zero;
  gemm_core(Ag, Bg, 64, Cc, 64, As, Bs, wave, lane, acc);
  int rw = (wave >> 1) * 64, cw = (wave & 1) * 64;
  int q = lane >> 4, cl = lane & 15;
  unsigned short* yb = ycat + (size_t)bl * Cc * KKc + (size_t)t * KKc;
  #pragma unroll
  for (int i = 0; i < 4; ++i)
    #pragma unroll
    for (int e = 0; e < 4; ++e) {
      int m2 = blockIdx.y * 128 + rw + i * 16 + q * 4 + e;
      if (m2 < 192) {
        int kk = m2 >> 6, o = m2 & 63;
        unsigned short* dst = yb + (size_t)o * 24 * KKc + kk * Nc;
        #pragma unroll
        for (int j = 0; j < 4; ++j)
          dst[blockIdx.x * 128 + cw + j * 16 + cl] = f2bf(acc[i][j][e]);
      }
    }
}

// ---------------------------------------------------------------------------
extern "C" void kernel_launch(void* const* d_in, const int* in_sizes, int n_in,
                              void* d_out, int out_size, void* d_ws, size_t ws_size,
                              hipStream_t stream) {
  const float* x     = (const float*)d_in[0];
  const float* W1    = (const float*)d_in[1];
  const float* W2    = (const float*)d_in[2];
  const float* W3    = (const float*)d_in[3];
  const float* bs    = (const float*)d_in[4];
  const float* Vs    = (const float*)d_in[5];
  const float* cheb  = (const float*)d_in[6];
  const float* Theta = (const float*)d_in[7];
  float* out = (float*)d_out;

  // ws_size-adaptive: 1 pass of 16 batches (needs 348.2 MB) or 2 passes of 8
  // (needs 222.3 MB, the R4-verified layout). Deterministic per harness.
  int passes, blcount;
  if (ws_size >= 348160000ULL) { passes = 1; blcount = 16; }
  else                         { passes = 2; blcount = 8;  }

  char* w = (char*)d_ws;
  size_t Y  = (size_t)blcount * Cc * KKc * 2;   // ycat bytes
  size_t A2 = (size_t)blcount * Nc * KKc * 2;   // Acat bytes
  unsigned short* ycat = (unsigned short*)w;
  unsigned short* Acat = (unsigned short*)(w + Y);
  unsigned short* ST   = (unsigned short*)(w + Y + A2);                 // 33.55 MB
  float* chebT         = (float*)(w + Y + A2 + 33554432);               // 12.58 MB
  unsigned short* xt2  = (unsigned short*)(w + Y + A2 + 46137344);      // 50.33 MB
  unsigned short* tcat = (unsigned short*)(w + Y + A2 + 96468992);      // 32 KB
  // Front-phase temps aliased into ycat (all dead before y2 writes ycat):
  unsigned short* lhsb = (unsigned short*)w;                // 2 MB
  unsigned short* rhsb = (unsigned short*)(w + 2097152);    // 2 MB
  unsigned short* sigT = (unsigned short*)(w + 4194304);    // 33.55 MB
  float* bsT           = (float*)(w + 37748736);            // 4.19 MB
  unsigned short* Vsbf = (unsigned short*)(w + 41943040);   // 2 MB (ends 44.04 MB <= 75.5)

  xprep_kernel<<<Bc * Nc / 4, 256, 0, stream>>>(x, W1, W2, W3, xt2, lhsb, rhsb);
  misc_kernel<<<1344, 256, 0, stream>>>(Vs, Theta, bs, Vsbf, tcat, bsT);
  // sigT[p][q] = sigmoid(sum_t rhsb[p,t]*lhsb[q,t] + bsT[p][q])
  mfma_gemm_bt<2><<<dim3(8, 8, 16), 256, 0, stream>>>(
      rhsb, lhsb, sigT, bsT, 64, Nc,
      (long long)Nc * 64, (long long)Nc * 64, (long long)Nc * Nc);
  // ST[b][j][i] = sum_kk sigT[b][j][kk] * Vs[i][kk]
  mfma_gemm_bt<0><<<dim3(8, 8, 16), 256, 0, stream>>>(
      sigT, Vsbf, ST, nullptr, Nc, Nc,
      (long long)Nc * Nc, 0LL, (long long)Nc * Nc);
  chebT_kernel<<<dim3(16, 16, 3), 256, 0, stream>>>(cheb, chebT);

  for (int pass = 0; pass < passes; ++pass) {
    int bbase = pass * blcount;
    masksoft_kernel<<<blcount * Nc, 256, 0, stream>>>(chebT, ST, Acat, bbase);
    y2_gemm<<<dim3(Nc / 128, 2, blcount * 24), 256, 0, stream>>>(tcat, xt2, ycat, bbase);
    // out[b][m][o*24+t] = relu( sum_{kk<3072} Acat[bl][m][kk] * ycat[bl][c''][kk] )
    mfma_gemm_bt<1><<<dim3(Cc / 128, Nc / 128, blcount), 256, 0, stream>>>(
        Acat, ycat, out + (size_t)bbase * Nc * Cc, nullptr, KKc, Cc,
        (long long)Nc * KKc, (long long)Cc * KKc, (long long)Nc * Cc);
  }
}